// Round 12
// baseline (179.609 us; speedup 1.0000x reference)
//
#include <hip/hip_runtime.h>
#include <stdint.h>

typedef unsigned short u16;
typedef __bf16 bf16x8 __attribute__((ext_vector_type(8)));
typedef float f32x4 __attribute__((ext_vector_type(4)));
typedef unsigned short ushort8 __attribute__((ext_vector_type(8)));
typedef unsigned short ushort4v __attribute__((ext_vector_type(4)));

#define MFMA __builtin_amdgcn_mfma_f32_16x16x32_bf16
#define EXP2 __builtin_amdgcn_exp2f

__device__ __forceinline__ u16 f2bf(float f){
  uint32_t u = __builtin_bit_cast(uint32_t, f);
  u += 0x7fffu + ((u >> 16) & 1u);
  return (u16)(u >> 16);
}
__device__ __forceinline__ float bf2f(u16 h){
  uint32_t u = ((uint32_t)h) << 16;
  return __builtin_bit_cast(float, u);
}
__device__ __forceinline__ uint32_t cvtpk(float lo, float hi){
  uint32_t r;
  asm("v_cvt_pk_bf16_f32 %0, %1, %2" : "=v"(r) : "v"(lo), "v"(hi));
  return r;
}
__device__ __forceinline__ bf16x8 ld8(const u16* p){
  return __builtin_bit_cast(bf16x8, *(const ushort8*)p);
}
__device__ __forceinline__ void gload16(const void* g, void* l){
  __builtin_amdgcn_global_load_lds((__attribute__((address_space(1))) void*)(void*)g,
                                   (__attribute__((address_space(3))) void*)l, 16, 0, 0);
}

// ---------------- fused preprocessing: conv8 | tr(qkv_w) | tr(proj_w) | relconv ----------------
// One launch instead of four (saves ~3 launch/tail overheads).
// blocks [0,1536): f32->bf16 convert of X (8 elems/thread)
// blocks [1536,1968): transpose+convert qkv_w (768x2304 -> 2304x768), 12x36 tiles
// blocks [1968,2112): transpose+convert proj_w (768x768), 12x12 tiles
// blocks [2112,2176): rel_pos tables *8, bf16, padded

__device__ __forceinline__ void tr_body(const float* __restrict__ in, u16* __restrict__ out,
                                        int R, int Cc, int bx, int by, int t, float* tile /*64x65*/){
  int r0 = bx*64, c0 = by*64;
  int c = t & 63, r4 = t >> 6;
  for (int i = 0; i < 16; ++i)
    tile[(r4 + i*4)*65 + c] = in[(size_t)(r0 + r4 + i*4)*Cc + c0 + c];
  __syncthreads();
  for (int i = 0; i < 16; ++i){
    int rr = r4 + i*4;
    out[(size_t)(c0 + rr)*R + r0 + c] = f2bf(tile[c*65 + rr]);
  }
}

__global__ __launch_bounds__(256) void k_prep(const float* __restrict__ X32,
                                              const float* __restrict__ qkvw,
                                              const float* __restrict__ projw,
                                              const float* __restrict__ rposh,
                                              const float* __restrict__ rposw,
                                              u16* __restrict__ Xb, u16* __restrict__ W1T,
                                              u16* __restrict__ PT,
                                              u16* __restrict__ rh8, u16* __restrict__ rw8){
  __shared__ float tile[64*65];
  const int b = blockIdx.x, t = threadIdx.x;
  if (b < 1536){
    int i = b*256 + t;
    const float4* p = (const float4*)X32;
    float4 a = p[i*2], c = p[i*2+1];
    ushort8 o;
    o[0]=f2bf(a.x); o[1]=f2bf(a.y); o[2]=f2bf(a.z); o[3]=f2bf(a.w);
    o[4]=f2bf(c.x); o[5]=f2bf(c.y); o[6]=f2bf(c.z); o[7]=f2bf(c.w);
    ((ushort8*)Xb)[i] = o;
  } else if (b < 1968){
    int bb = b - 1536;
    tr_body(qkvw, W1T, 768, 2304, bb % 12, bb / 12, t, tile);
  } else if (b < 2112){
    int bb = b - 1968;
    tr_body(projw, PT, 768, 768, bb % 12, bb / 12, t, tile);
  } else {
    int i = (b - 2112)*256 + t;          // [0,16384)
    if (i < 8192)      rh8[i] = f2bf(i < 8128 ? rposh[i]*8.0f : 0.0f);
    else { int j = i - 8192; rw8[j] = f2bf(j < 8128 ? rposw[j]*8.0f : 0.0f); }
  }
}

// ---------------- QKV GEMM: (4096x768)x(768x2304), split to Qs/Kf/Vf ----------------
// K/V stored fragment-linear so k_flash loads are pure contiguous bursts:
//   Kf[h][kb][f=ct*2+ks][lane=lg*16+lr][e] = K[kb*64+ct*16+lr][ks*32+lg*8+e]
//   Vf[h][kb][f=dt*2+ks][lane=lg*16+lr][e] = V[kb*64+ks*32+lg*8+e][dt*16+lr]

__global__ __launch_bounds__(256) void k_qkv(const u16* __restrict__ X, const u16* __restrict__ WT,
                                             const float* __restrict__ bias,
                                             u16* __restrict__ Qs, u16* __restrict__ Kf, u16* __restrict__ Vf){
  __shared__ __align__(16) u16 At[128*64];
  __shared__ __align__(16) u16 Bt[128*64];
  __shared__ __align__(16) u16 Tt[4][64*72];   // per-wave repack tile, pad 72 keeps 16B align
  const int tid = threadIdx.x, lane = tid & 63, w = tid >> 6;
  const int m0 = blockIdx.x*128, n0 = blockIdx.y*128;
  const int wr = (w >> 1)*64, wc = (w & 1)*64;
  const int lr = lane & 15, lg = lane >> 4;
  const int srcRow = w*32 + (lane >> 3);
  const int srcK   = (lane & 7)*8;
  f32x4 acc[4][4] = {};
  for (int kt = 0; kt < 12; ++kt){
    const int kbase = kt*64;
    for (int s = 0; s < 4; ++s){
      gload16(X  + (size_t)(m0 + srcRow + s*8)*768 + kbase + srcK, At + (w*32 + s*8)*64);
      gload16(WT + (size_t)(n0 + srcRow + s*8)*768 + kbase + srcK, Bt + (w*32 + s*8)*64);
    }
    __syncthreads();
    bf16x8 af[2][4], bfr[2][4];
    for (int ks = 0; ks < 2; ++ks)
      for (int i = 0; i < 4; ++i){
        af[ks][i]  = ld8(At + (wr + i*16 + lr)*64 + ks*32 + lg*8);
        bfr[ks][i] = ld8(Bt + (wc + i*16 + lr)*64 + ks*32 + lg*8);
      }
    for (int ks = 0; ks < 2; ++ks)
      for (int mi = 0; mi < 4; ++mi)
        for (int ni = 0; ni < 4; ++ni)
          acc[mi][ni] = MFMA(af[ks][mi], bfr[ks][ni], acc[mi][ni], 0, 0, 0);
    __syncthreads();
  }
  const int colbase = n0 + wc;            // 64-aligned -> s3/hh uniform per wave
  const int s3 = colbase / 768;
  const int hh = (colbase % 768) >> 6;
  const int rowbase = m0 + wr;            // 64-aligned -> kb uniform per wave
  if (s3 == 0){
    for (int mi = 0; mi < 4; ++mi)
      for (int ni = 0; ni < 4; ++ni){
        float bv = bias[colbase + ni*16 + lr];
        for (int r = 0; r < 4; ++r){
          int row = rowbase + mi*16 + lg*4 + r;
          // Q pre-scaled by head_dim^-0.5 * log2(e) so softmax runs in exp2 domain
          Qs[((size_t)hh*4096 + row)*64 + ni*16 + lr] =
              f2bf((acc[mi][ni][r] + bv)*(0.125f*1.44269504f));
        }
      }
  } else {
    u16* T = Tt[w];
    for (int mi = 0; mi < 4; ++mi)
      for (int ni = 0; ni < 4; ++ni){
        float bv = bias[colbase + ni*16 + lr];
        for (int r = 0; r < 4; ++r){
          int row_l = mi*16 + lg*4 + r, col_l = ni*16 + lr;
          u16 v = f2bf(acc[mi][ni][r] + bv);
          if (s3 == 1) T[row_l*72 + col_l] = v;     // K: [token][d]
          else         T[col_l*72 + row_l] = v;     // V: [d][token] (transposed)
        }
      }
    // same-wave LDS write->read; no cross-wave sharing, compiler inserts lgkmcnt
    const int kb = rowbase >> 6;
    u16* dst = (s3 == 1 ? Kf : Vf) + ((size_t)hh*64 + kb)*4096 + lane*8;
    #pragma unroll
    for (int f = 0; f < 8; ++f){
      int a = f >> 1, ks = f & 1;
      *(ushort8*)&dst[f*512] = *(const ushort8*)&T[(a*16 + lr)*72 + ks*32 + lg*8];
    }
  }
}

// ---------------- rel_h / rel_w via MFMA; grid (64 qh, 12 h) ----------------

__global__ __launch_bounds__(256) void k_rel(const u16* __restrict__ Qs, const u16* __restrict__ Rh8,
                                             const u16* __restrict__ Rw8,
                                             u16* __restrict__ relh, u16* __restrict__ relw){
  __shared__ __align__(16) u16 Ql[64*64];
  __shared__ __align__(16) u16 Rhl[64*64];
  __shared__ __align__(16) u16 Rwl[128*64];
  const int tid = threadIdx.x, lane = tid & 63, w = tid >> 6;
  const int qh = blockIdx.x, h = blockIdx.y;
  const int lr = lane & 15, lg = lane >> 4;
  for (int j = 0; j < 2; ++j){
    int ch = tid + 256*j;             // 0..511
    int row = ch >> 3, k8 = (ch & 7)*8;
    *(ushort8*)&Ql[row*64 + k8]  = *(const ushort8*)&Qs[((size_t)h*4096 + qh*64 + row)*64 + k8];
    *(ushort8*)&Rhl[row*64 + k8] = *(const ushort8*)&Rh8[(qh + row)*64 + k8];
  }
  for (int j = 0; j < 4; ++j){
    int ch = tid + 256*j;             // 0..1023
    int row = ch >> 3, k8 = (ch & 7)*8;
    *(ushort8*)&Rwl[row*64 + k8] = *(const ushort8*)&Rw8[row*64 + k8];
  }
  __syncthreads();
  bf16x8 a[2];
  for (int ks = 0; ks < 2; ++ks) a[ks] = ld8(Ql + (w*16 + lr)*64 + ks*32 + lg*8);
  // rel_h[qw][kh] = (Q . rel_pos_h[qh+63-kh]) ; computed as Q @ Rh[qh+c]^T, kh = 63-c
  for (int ct = 0; ct < 4; ++ct){
    f32x4 c = {};
    for (int ks = 0; ks < 2; ++ks)
      c = MFMA(a[ks], ld8(Rhl + (ct*16 + lr)*64 + ks*32 + lg*8), c, 0, 0, 0);
    int kh = 63 - (ct*16 + lr);
    for (int r = 0; r < 4; ++r){
      int qw = w*16 + lg*4 + r;
      relh[((size_t)h*4096 + qh*64 + qw)*64 + kh] = f2bf(c[r]);
    }
  }
  // rel_w[qw][kw] = (Q . rel_pos_w[qw+63-kw]) ; full band, keep valid kw
  for (int ct = 0; ct < 8; ++ct){
    f32x4 c = {};
    for (int ks = 0; ks < 2; ++ks)
      c = MFMA(a[ks], ld8(Rwl + (ct*16 + lr)*64 + ks*32 + lg*8), c, 0, 0, 0);
    int cc = ct*16 + lr;
    for (int r = 0; r < 4; ++r){
      int qw = w*16 + lg*4 + r;
      int kw = qw + 63 - cc;
      if (kw >= 0 && kw < 64)
        relw[((size_t)h*4096 + qh*64 + qw)*64 + kw] = f2bf(c[r]);
    }
  }
}

// ---------------- flash attention; flat grid 768, 4 waves ----------------
// R12: split the operand traffic across the two memory pipes.
//  - K: per-wave GLOBAL fragment loads, register double-buffered (R8-proven,
//    80 VGPR no-spill). L2 demand ~half of R8 since V no longer comes from L2.
//  - V: staged to LDS once per block via global_load_lds, shared by 4 waves,
//    double-buffered. (R11 had BOTH K and V in LDS -> ~80% LDS-pipe utilization,
//    the binding resource: 24KB LDS traffic/wave-iter x 12 waves vs 85B/cy.)
// LDS traffic/wave-iter drops 24KB -> ~13KB; VMEM/L2 ~11 TB/s. Both pipes <50%.
// R11 lazy softmax kept: no cross-lane ops steady-state; lsum reduced in epilogue.
// Swapped operands: QK^T as mfma(K,Q)->S^T, PV as mfma(V^T,P^T)->O^T.
// Head->XCD affinity (768 = 8*96): <=2 heads (2MB KV) per XCD L2.
// launch_bounds(256,3): arch-VGPR budget ~84; spill tripwire = FETCH_SIZE blowup.

__global__ __launch_bounds__(256, 3) void k_flash(const u16* __restrict__ Qs, const u16* __restrict__ Kf,
                                                  const u16* __restrict__ Vf,
                                                  const u16* __restrict__ relh, const u16* __restrict__ relw,
                                                  u16* __restrict__ Ob){
  __shared__ __align__(16) u16 Vl[2][4096];       // 8KB per V tile (fragment-linear copy)
  __shared__ __align__(16) char Psm[4][2048];     // per-wave P tile, XOR-swizzled
  const int tid = threadIdx.x, lane = tid & 63, w = tid >> 6;
  const int b = blockIdx.x;
  const int p = (b & 7)*96 + (b >> 3);         // head->XCD affinity remap (768 = 8*96)
  const int h = p >> 6, qb = p & 63;
  const int lr = lane & 15, lg = lane >> 4;
  const size_t hq = (size_t)h*4096;
  const int q = qb*64 + w*16 + lr;             // this lane's q row (S^T column)
  char* Pb = Psm[w];
  const int swz = (lr & 7) << 4;

  const bf16x8 qf0 = ld8(Qs + (hq + q)*64 + lg*8);
  const bf16x8 qf1 = ld8(Qs + (hq + q)*64 + 32 + lg*8);
  // rel_w bias row unpacked to f32 once
  float rwf[4][4];
  #pragma unroll
  for (int ct = 0; ct < 4; ++ct){
    ushort4v t = *(const ushort4v*)&relw[(hq + q)*64 + ct*16 + lg*4];
    #pragma unroll
    for (int r = 0; r < 4; ++r) rwf[ct][r] = bf2f(t[r]);
  }

  const u16* KfH = Kf + (size_t)h*262144 + lane*8;   // + kb*4096 + f*512 (per-wave K)
  const u16* VfH = Vf + (size_t)h*262144;            // block V staging base
  const u16* rhbase = relh + (hq + q)*64;

  float m = -1e30f, lsum = 0.f;                // lsum is PER-LANE partial (reduced at end)
  f32x4 oacc[4] = {};                          // O^T: rows d = dt*16+lg*4+r, col q = lr
  bf16x8 kA[8], kB[8];

  auto loadK = [&](bf16x8 (&dst)[8], int kbi){
    const u16* kp = KfH + kbi*4096;
    #pragma unroll
    for (int f = 0; f < 8; ++f) dst[f] = ld8(kp + f*512);
  };
  // wave w stages 1KB chunks {2w,2w+1} of V; LDS dest wave-uniform (HW adds lane*16B)
  auto stageV = [&](int buf, int kb){
    const u16* vs = VfH + kb*4096 + w*1024 + lane*8;
    gload16(vs,       &Vl[buf][w*1024]);
    gload16(vs + 512, &Vl[buf][w*1024 + 512]);
  };

#define ITERBODY(KB, KC, BUF)                                                 \
  {                                                                           \
    const u16* VL = Vl[BUF] + lane*8;                                         \
    const float rhv = bf2f(rhbase[KB]);                                       \
    f32x4 s[4];                                                               \
    _Pragma("unroll")                                                         \
    for (int ct = 0; ct < 4; ++ct){                                           \
      _Pragma("unroll")                                                       \
      for (int r = 0; r < 4; ++r) s[ct][r] = rhv + rwf[ct][r];                \
    }                                                                         \
    __builtin_amdgcn_s_setprio(1);                                            \
    _Pragma("unroll")                                                         \
    for (int ct = 0; ct < 4; ++ct){                                           \
      s[ct] = MFMA(KC[ct*2],   qf0, s[ct], 0, 0, 0);                          \
      s[ct] = MFMA(KC[ct*2+1], qf1, s[ct], 0, 0, 0);                          \
    }                                                                         \
    __builtin_amdgcn_s_setprio(0);                                            \
    /* lane-local max over own 16 values */                                   \
    float pm0 = fmaxf(fmaxf(s[0][0], s[0][1]), fmaxf(fmaxf(s[0][2], s[0][3]), \
                      fmaxf(s[1][0], s[1][1])));                              \
    float pm1 = fmaxf(fmaxf(s[1][2], s[1][3]), fmaxf(fmaxf(s[2][0], s[2][1]), \
                      fmaxf(s[2][2], s[2][3])));                              \
    float pm2 = fmaxf(fmaxf(s[3][0], s[3][1]), fmaxf(s[3][2], s[3][3]));      \
    float pm = fmaxf(fmaxf(pm0, pm1), pm2);                                   \
    /* lazy rescale: cross-lane reduce only when some row max grew */         \
    if (__any(pm > m)){                                                       \
      pm = fmaxf(pm, __shfl_xor(pm, 16, 64));                                 \
      pm = fmaxf(pm, __shfl_xor(pm, 32, 64));                                 \
      const float nm = fmaxf(m, pm);                                          \
      const float corr = EXP2(m - nm);                                        \
      m = nm;                                                                 \
      lsum *= corr;                                                           \
      _Pragma("unroll")                                                       \
      for (int dt = 0; dt < 4; ++dt)                                          \
        _Pragma("unroll")                                                     \
        for (int r = 0; r < 4; ++r) oacc[dt][r] *= corr;                      \
    }                                                                         \
    float rs = 0.f;                                                           \
    _Pragma("unroll")                                                         \
    for (int ct = 0; ct < 4; ++ct){                                           \
      _Pragma("unroll")                                                       \
      for (int r = 0; r < 4; ++r){                                            \
        float p2 = EXP2(s[ct][r] - m);                                        \
        s[ct][r] = p2; rs += p2;                                              \
      }                                                                       \
    }                                                                         \
    lsum += rs;   /* per-lane partial; no shfl here */                        \
    _Pragma("unroll")                                                         \
    for (int ct = 0; ct < 4; ++ct){                                           \
      uint2 uv;                                                               \
      uv.x = cvtpk(s[ct][0], s[ct][1]);                                       \
      uv.y = cvtpk(s[ct][2], s[ct][3]);                                       \
      *(uint2*)(Pb + ((lr*128 + ct*32 + lg*8) ^ swz)) = uv;                   \
    }                                                                         \
    bf16x8 pa0 = __builtin_bit_cast(bf16x8, *(ushort8*)(Pb + ((lr*128      + lg*16) ^ swz))); \
    bf16x8 pa1 = __builtin_bit_cast(bf16x8, *(ushort8*)(Pb + ((lr*128 + 64 + lg*16) ^ swz))); \
    __builtin_amdgcn_s_setprio(1);                                            \
    _Pragma("unroll")                                                         \
    for (int dt = 0; dt < 4; ++dt){                                           \
      oacc[dt] = MFMA(ld8(VL + (dt*2)*512),   pa0, oacc[dt], 0, 0, 0);        \
      oacc[dt] = MFMA(ld8(VL + (dt*2+1)*512), pa1, oacc[dt], 0, 0, 0);        \
    }                                                                         \
    __builtin_amdgcn_s_setprio(0);                                            \
  }

  loadK(kA, 0);
  stageV(0, 0);
  __syncthreads();                     // drains vmcnt -> V tile 0 ready
  for (int kb2 = 0; kb2 < 64; kb2 += 2){
    stageV(1, (kb2 + 1) & 63);         // issue next V tile (overlaps compute)
    loadK(kB, (kb2 + 1) & 63);         // prefetch next K into regs
    ITERBODY(kb2, kA, 0)
    __syncthreads();                   // V buf1 staged + all waves done with buf0
    stageV(0, (kb2 + 2) & 63);
    loadK(kA, (kb2 + 2) & 63);
    ITERBODY(kb2 + 1, kB, 1)
    __syncthreads();
  }
#undef ITERBODY

  // epilogue: single cross-lane sum reduce of the per-lane lsum partials
  lsum += __shfl_xor(lsum, 16, 64);
  lsum += __shfl_xor(lsum, 32, 64);
  const float inv = 1.0f / lsum;
  #pragma unroll
  for (int dt = 0; dt < 4; ++dt){
    ushort4v pk;
    #pragma unroll
    for (int r = 0; r < 4; ++r) pk[r] = f2bf(oacc[dt][r]*inv);
    *(ushort4v*)&Ob[(size_t)q*768 + h*64 + dt*16 + lg*4] = pk;
  }
}

// ---------------- proj GEMM: (4096x768)x(768x768) + b -> f32 out ----------------

__global__ __launch_bounds__(256) void k_proj(const u16* __restrict__ A, const u16* __restrict__ WT,
                                              const float* __restrict__ bias, float* __restrict__ out){
  __shared__ __align__(16) u16 At[128*64];
  __shared__ __align__(16) u16 Bt[128*64];
  const int tid = threadIdx.x, lane = tid & 63, w = tid >> 6;
  const int m0 = blockIdx.x*128, n0 = blockIdx.y*128;
  const int wr = (w >> 1)*64, wc = (w & 1)*64;
  const int lr = lane & 15, lg = lane >> 4;
  const int srcRow = w*32 + (lane >> 3);
  const int srcK   = (lane & 7)*8;
  f32x4 acc[4][4] = {};
  for (int kt = 0; kt < 12; ++kt){
    const int kbase = kt*64;
    for (int s = 0; s < 4; ++s){
      gload16(A  + (size_t)(m0 + srcRow + s*8)*768 + kbase + srcK, At + (w*32 + s*8)*64);
      gload16(WT + (size_t)(n0 + srcRow + s*8)*768 + kbase + srcK, Bt + (w*32 + s*8)*64);
    }
    __syncthreads();
    bf16x8 af[2][4], bfr[2][4];
    for (int ks = 0; ks < 2; ++ks)
      for (int i = 0; i < 4; ++i){
        af[ks][i]  = ld8(At + (wr + i*16 + lr)*64 + ks*32 + lg*8);
        bfr[ks][i] = ld8(Bt + (wc + i*16 + lr)*64 + ks*32 + lg*8);
      }
    for (int ks = 0; ks < 2; ++ks)
      for (int mi = 0; mi < 4; ++mi)
        for (int ni = 0; ni < 4; ++ni)
          acc[mi][ni] = MFMA(af[ks][mi], bfr[ks][ni], acc[mi][ni], 0, 0, 0);
    __syncthreads();
  }
  for (int mi = 0; mi < 4; ++mi)
    for (int ni = 0; ni < 4; ++ni){
      int col = n0 + wc + ni*16 + lr;
      float bv = bias[col];
      for (int r = 0; r < 4; ++r){
        int row = m0 + wr + mi*16 + lg*4 + r;
        out[(size_t)row*768 + col] = acc[mi][ni][r] + bv;
      }
    }
}

// ---------------- launch ----------------

extern "C" void kernel_launch(void* const* d_in, const int* in_sizes, int n_in,
                              void* d_out, int out_size, void* d_ws, size_t ws_size,
                              hipStream_t stream){
  const float* X32   = (const float*)d_in[0];
  const float* qkvw  = (const float*)d_in[1];
  const float* qkvb  = (const float*)d_in[2];
  const float* projw = (const float*)d_in[3];
  const float* projb = (const float*)d_in[4];
  const float* rposh = (const float*)d_in[5];
  const float* rposw = (const float*)d_in[6];

  u16* Xb  = (u16*)d_ws;            // 4096*768
  u16* W1T = Xb  + 3145728;         // 2304*768
  u16* PT  = W1T + 1769472;         // 768*768
  u16* Rh8 = PT  + 589824;          // 128*64 (padded)
  u16* Rw8 = Rh8 + 8192;            // 128*64 (padded)
  u16* Qs  = Rw8 + 8192;            // 12*4096*64 (pre-scaled by 1/8 * log2e)
  u16* Kf  = Qs  + 3145728;         // fragment-linear K [12][64][8][64][8]
  u16* Vf  = Kf  + 3145728;         // fragment-linear V^T [12][64][8][64][8]
  u16* Rlh = Vf  + 3145728;         // [12][4096][64]
  u16* Rlw = Rlh + 3145728;         // [12][4096][64]
  u16* Ob  = Rlw + 3145728;         // [4096][768]
  float* out = (float*)d_out;

  k_prep <<<2176, 256, 0, stream>>>(X32, qkvw, projw, rposh, rposw, Xb, W1T, PT, Rh8, Rw8);
  k_qkv  <<<dim3(32, 18), 256, 0, stream>>>(Xb, W1T, qkvb, Qs, Kf, Vf);
  k_rel  <<<dim3(64, 12), 256, 0, stream>>>(Qs, Rh8, Rw8, Rlh, Rlw);
  k_flash<<<768, 256, 0, stream>>>(Qs, Kf, Vf, Rlh, Rlw, Ob);
  k_proj <<<dim3(32, 6), 256, 0, stream>>>(Ob, PT, projb, out);
}

// Round 13
// 176.299 us; speedup vs baseline: 1.0188x; 1.0188x over previous
//
#include <hip/hip_runtime.h>
#include <stdint.h>

typedef unsigned short u16;
typedef __bf16 bf16x8 __attribute__((ext_vector_type(8)));
typedef float f32x4 __attribute__((ext_vector_type(4)));
typedef unsigned short ushort8 __attribute__((ext_vector_type(8)));
typedef unsigned short ushort4v __attribute__((ext_vector_type(4)));

#define MFMA __builtin_amdgcn_mfma_f32_16x16x32_bf16
#define EXP2 __builtin_amdgcn_exp2f

__device__ __forceinline__ u16 f2bf(float f){
  uint32_t u = __builtin_bit_cast(uint32_t, f);
  u += 0x7fffu + ((u >> 16) & 1u);
  return (u16)(u >> 16);
}
__device__ __forceinline__ float bf2f(u16 h){
  uint32_t u = ((uint32_t)h) << 16;
  return __builtin_bit_cast(float, u);
}
__device__ __forceinline__ uint32_t cvtpk(float lo, float hi){
  uint32_t r;
  asm("v_cvt_pk_bf16_f32 %0, %1, %2" : "=v"(r) : "v"(lo), "v"(hi));
  return r;
}
__device__ __forceinline__ bf16x8 ld8(const u16* p){
  return __builtin_bit_cast(bf16x8, *(const ushort8*)p);
}
__device__ __forceinline__ void gload16(const void* g, void* l){
  __builtin_amdgcn_global_load_lds((__attribute__((address_space(1))) void*)(void*)g,
                                   (__attribute__((address_space(3))) void*)l, 16, 0, 0);
}

// ---------------- fused preprocessing: conv8 | tr(qkv_w) | tr(proj_w) | relconv ----------------

__device__ __forceinline__ void tr_body(const float* __restrict__ in, u16* __restrict__ out,
                                        int R, int Cc, int bx, int by, int t, float* tile /*64x65*/){
  int r0 = bx*64, c0 = by*64;
  int c = t & 63, r4 = t >> 6;
  for (int i = 0; i < 16; ++i)
    tile[(r4 + i*4)*65 + c] = in[(size_t)(r0 + r4 + i*4)*Cc + c0 + c];
  __syncthreads();
  for (int i = 0; i < 16; ++i){
    int rr = r4 + i*4;
    out[(size_t)(c0 + rr)*R + r0 + c] = f2bf(tile[c*65 + rr]);
  }
}

__global__ __launch_bounds__(256) void k_prep(const float* __restrict__ X32,
                                              const float* __restrict__ qkvw,
                                              const float* __restrict__ projw,
                                              const float* __restrict__ rposh,
                                              const float* __restrict__ rposw,
                                              u16* __restrict__ Xb, u16* __restrict__ W1T,
                                              u16* __restrict__ PT,
                                              u16* __restrict__ rh8, u16* __restrict__ rw8){
  __shared__ float tile[64*65];
  const int b = blockIdx.x, t = threadIdx.x;
  if (b < 1536){
    int i = b*256 + t;
    const float4* p = (const float4*)X32;
    float4 a = p[i*2], c = p[i*2+1];
    ushort8 o;
    o[0]=f2bf(a.x); o[1]=f2bf(a.y); o[2]=f2bf(a.z); o[3]=f2bf(a.w);
    o[4]=f2bf(c.x); o[5]=f2bf(c.y); o[6]=f2bf(c.z); o[7]=f2bf(c.w);
    ((ushort8*)Xb)[i] = o;
  } else if (b < 1968){
    int bb = b - 1536;
    tr_body(qkvw, W1T, 768, 2304, bb % 12, bb / 12, t, tile);
  } else if (b < 2112){
    int bb = b - 1968;
    tr_body(projw, PT, 768, 768, bb % 12, bb / 12, t, tile);
  } else {
    int i = (b - 2112)*256 + t;          // [0,16384)
    if (i < 8192)      rh8[i] = f2bf(i < 8128 ? rposh[i]*8.0f : 0.0f);
    else { int j = i - 8192; rw8[j] = f2bf(j < 8128 ? rposw[j]*8.0f : 0.0f); }
  }
}

// ---------------- QKV GEMM: (4096x768)x(768x2304), split to Qs/Kf/Vf ----------------
// K/V stored fragment-linear so k_flash staging is pure contiguous bursts:
//   Kf[h][kb][f=ct*2+ks][lane=lg*16+lr][e] = K[kb*64+ct*16+lr][ks*32+lg*8+e]
//   Vf[h][kb][f=dt*2+ks][lane=lg*16+lr][e] = V[kb*64+ks*32+lg*8+e][dt*16+lr]

__global__ __launch_bounds__(256) void k_qkv(const u16* __restrict__ X, const u16* __restrict__ WT,
                                             const float* __restrict__ bias,
                                             u16* __restrict__ Qs, u16* __restrict__ Kf, u16* __restrict__ Vf){
  __shared__ __align__(16) u16 At[128*64];
  __shared__ __align__(16) u16 Bt[128*64];
  __shared__ __align__(16) u16 Tt[4][64*72];   // per-wave repack tile, pad 72 keeps 16B align
  const int tid = threadIdx.x, lane = tid & 63, w = tid >> 6;
  const int m0 = blockIdx.x*128, n0 = blockIdx.y*128;
  const int wr = (w >> 1)*64, wc = (w & 1)*64;
  const int lr = lane & 15, lg = lane >> 4;
  const int srcRow = w*32 + (lane >> 3);
  const int srcK   = (lane & 7)*8;
  f32x4 acc[4][4] = {};
  for (int kt = 0; kt < 12; ++kt){
    const int kbase = kt*64;
    for (int s = 0; s < 4; ++s){
      gload16(X  + (size_t)(m0 + srcRow + s*8)*768 + kbase + srcK, At + (w*32 + s*8)*64);
      gload16(WT + (size_t)(n0 + srcRow + s*8)*768 + kbase + srcK, Bt + (w*32 + s*8)*64);
    }
    __syncthreads();
    bf16x8 af[2][4], bfr[2][4];
    for (int ks = 0; ks < 2; ++ks)
      for (int i = 0; i < 4; ++i){
        af[ks][i]  = ld8(At + (wr + i*16 + lr)*64 + ks*32 + lg*8);
        bfr[ks][i] = ld8(Bt + (wc + i*16 + lr)*64 + ks*32 + lg*8);
      }
    for (int ks = 0; ks < 2; ++ks)
      for (int mi = 0; mi < 4; ++mi)
        for (int ni = 0; ni < 4; ++ni)
          acc[mi][ni] = MFMA(af[ks][mi], bfr[ks][ni], acc[mi][ni], 0, 0, 0);
    __syncthreads();
  }
  const int colbase = n0 + wc;            // 64-aligned -> s3/hh uniform per wave
  const int s3 = colbase / 768;
  const int hh = (colbase % 768) >> 6;
  const int rowbase = m0 + wr;            // 64-aligned -> kb uniform per wave
  if (s3 == 0){
    for (int mi = 0; mi < 4; ++mi)
      for (int ni = 0; ni < 4; ++ni){
        float bv = bias[colbase + ni*16 + lr];
        for (int r = 0; r < 4; ++r){
          int row = rowbase + mi*16 + lg*4 + r;
          // Q pre-scaled by head_dim^-0.5 * log2(e) so softmax runs in exp2 domain
          Qs[((size_t)hh*4096 + row)*64 + ni*16 + lr] =
              f2bf((acc[mi][ni][r] + bv)*(0.125f*1.44269504f));
        }
      }
  } else {
    u16* T = Tt[w];
    for (int mi = 0; mi < 4; ++mi)
      for (int ni = 0; ni < 4; ++ni){
        float bv = bias[colbase + ni*16 + lr];
        for (int r = 0; r < 4; ++r){
          int row_l = mi*16 + lg*4 + r, col_l = ni*16 + lr;
          u16 v = f2bf(acc[mi][ni][r] + bv);
          if (s3 == 1) T[row_l*72 + col_l] = v;     // K: [token][d]
          else         T[col_l*72 + row_l] = v;     // V: [d][token] (transposed)
        }
      }
    // same-wave LDS write->read; no cross-wave sharing, compiler inserts lgkmcnt
    const int kb = rowbase >> 6;
    u16* dst = (s3 == 1 ? Kf : Vf) + ((size_t)hh*64 + kb)*4096 + lane*8;
    #pragma unroll
    for (int f = 0; f < 8; ++f){
      int a = f >> 1, ks = f & 1;
      *(ushort8*)&dst[f*512] = *(const ushort8*)&T[(a*16 + lr)*72 + ks*32 + lg*8];
    }
  }
}

// ---------------- rel_h / rel_w via MFMA; grid (64 qh, 12 h) ----------------

__global__ __launch_bounds__(256) void k_rel(const u16* __restrict__ Qs, const u16* __restrict__ Rh8,
                                             const u16* __restrict__ Rw8,
                                             u16* __restrict__ relh, u16* __restrict__ relw){
  __shared__ __align__(16) u16 Ql[64*64];
  __shared__ __align__(16) u16 Rhl[64*64];
  __shared__ __align__(16) u16 Rwl[128*64];
  const int tid = threadIdx.x, lane = tid & 63, w = tid >> 6;
  const int qh = blockIdx.x, h = blockIdx.y;
  const int lr = lane & 15, lg = lane >> 4;
  for (int j = 0; j < 2; ++j){
    int ch = tid + 256*j;             // 0..511
    int row = ch >> 3, k8 = (ch & 7)*8;
    *(ushort8*)&Ql[row*64 + k8]  = *(const ushort8*)&Qs[((size_t)h*4096 + qh*64 + row)*64 + k8];
    *(ushort8*)&Rhl[row*64 + k8] = *(const ushort8*)&Rh8[(qh + row)*64 + k8];
  }
  for (int j = 0; j < 4; ++j){
    int ch = tid + 256*j;             // 0..1023
    int row = ch >> 3, k8 = (ch & 7)*8;
    *(ushort8*)&Rwl[row*64 + k8] = *(const ushort8*)&Rw8[row*64 + k8];
  }
  __syncthreads();
  bf16x8 a[2];
  for (int ks = 0; ks < 2; ++ks) a[ks] = ld8(Ql + (w*16 + lr)*64 + ks*32 + lg*8);
  // rel_h[qw][kh] = (Q . rel_pos_h[qh+63-kh]) ; computed as Q @ Rh[qh+c]^T, kh = 63-c
  for (int ct = 0; ct < 4; ++ct){
    f32x4 c = {};
    for (int ks = 0; ks < 2; ++ks)
      c = MFMA(a[ks], ld8(Rhl + (ct*16 + lr)*64 + ks*32 + lg*8), c, 0, 0, 0);
    int kh = 63 - (ct*16 + lr);
    for (int r = 0; r < 4; ++r){
      int qw = w*16 + lg*4 + r;
      relh[((size_t)h*4096 + qh*64 + qw)*64 + kh] = f2bf(c[r]);
    }
  }
  // rel_w[qw][kw] = (Q . rel_pos_w[qw+63-kw]) ; full band, keep valid kw
  for (int ct = 0; ct < 8; ++ct){
    f32x4 c = {};
    for (int ks = 0; ks < 2; ++ks)
      c = MFMA(a[ks], ld8(Rwl + (ct*16 + lr)*64 + ks*32 + lg*8), c, 0, 0, 0);
    int cc = ct*16 + lr;
    for (int r = 0; r < 4; ++r){
      int qw = w*16 + lg*4 + r;
      int kw = qw + 63 - cc;
      if (kw >= 0 && kw < 64)
        relw[((size_t)h*4096 + qh*64 + qw)*64 + kw] = f2bf(c[r]);
    }
  }
}

// ---------------- flash attention; flat grid 768, 8 waves (512 thr) ----------------
// R13: in-block KV-split x2 on the R11 structure. Waves 0-3 (half 0) process KV
// tiles 0-31, waves 4-7 (half 1) tiles 32-63, SAME 64 q-rows (qt = w&3);
// pairwise merge (w, w+4) via LDS at the end (R8-proven math).
// -> 16 waves/CU (was 12): more latency hiding for the serial per-wave chain
//    (MFMA -> softmax -> P roundtrip -> PV) that caused R11's ~36% stall.
// KV staged per half, double-buffered; total staging traffic unchanged
// (each block stages only its 32 tiles; 2x q-rows share it).
// LDS 80KB -> 2 blocks/CU (160KB exact). Merge buffers REUSE the staging LDS
// after the final barrier. Per-wave register state identical to R11 (52 arch
// VGPR), (512,4) cap ~64 arch -> no spill expected; tripwire = FETCH_SIZE.
// R11 lazy softmax kept. Swapped operands; head->XCD affinity (768 = 8*96).

__global__ __launch_bounds__(512, 4) void k_flash(const u16* __restrict__ Qs, const u16* __restrict__ Kf,
                                                  const u16* __restrict__ Vf,
                                                  const u16* __restrict__ relh, const u16* __restrict__ relw,
                                                  u16* __restrict__ Ob){
  __shared__ __align__(16) char SMEM[81920];
  // loop phase:   Kl [2 half][2 buf][4096 u16] @0      (32KB)
  //               Vl [2 half][2 buf][4096 u16] @32768  (32KB)
  //               Psm [8][2048B]               @65536  (16KB)
  // merge phase:  Osm [8][16*68 f32] @0 (34816B) | MLsm [8][32 f32] @34816
  u16*  KlB = (u16*)SMEM;
  u16*  VlB = (u16*)(SMEM + 32768);
  const int tid = threadIdx.x, lane = tid & 63, w = tid >> 6;
  const int b = blockIdx.x;
  const int p = (b & 7)*96 + (b >> 3);         // head->XCD affinity remap (768 = 8*96)
  const int h = p >> 6, qb = p & 63;
  const int half = w >> 2, qt = w & 3;
  const int lr = lane & 15, lg = lane >> 4;
  const size_t hq = (size_t)h*4096;
  const int q = qb*64 + qt*16 + lr;            // this lane's q row (S^T column)
  char* Pb = SMEM + 65536 + w*2048;
  const int swz = (lr & 7) << 4;
  const int kb0 = half*32;

  const bf16x8 qf0 = ld8(Qs + (hq + q)*64 + lg*8);
  const bf16x8 qf1 = ld8(Qs + (hq + q)*64 + 32 + lg*8);
  // rel_w bias row unpacked to f32 once
  float rwf[4][4];
  #pragma unroll
  for (int ct = 0; ct < 4; ++ct){
    ushort4v t = *(const ushort4v*)&relw[(hq + q)*64 + ct*16 + lg*4];
    #pragma unroll
    for (int r = 0; r < 4; ++r) rwf[ct][r] = bf2f(t[r]);
  }

  const u16* KfH = Kf + (size_t)h*262144;      // + kb*4096
  const u16* VfH = Vf + (size_t)h*262144;
  const u16* rhbase = relh + (hq + q)*64;

  float m = -1e30f, lsum = 0.f;                // lsum per-lane partial (reduced at merge)
  f32x4 oacc[4] = {};                          // O^T: rows d = dt*16+lg*4+r, col q = lr

  // staging: wave w covers 2KB chunk (w&3) of its half's K tile + V tile.
  // LDS dest wave-uniform (HW adds lane*16B); src per-lane +lane*8 elems.
  auto stage = [&](int buf, int kl){
    const int tile = half*32 + kl;
    const int i4 = (w & 3)*1024;
    const u16* ks = KfH + tile*4096 + i4 + lane*8;
    const u16* vs = VfH + tile*4096 + i4 + lane*8;
    u16* kd = KlB + (half*2 + buf)*4096 + i4;
    u16* vd = VlB + (half*2 + buf)*4096 + i4;
    gload16(ks,       kd);
    gload16(ks + 512, kd + 512);
    gload16(vs,       vd);
    gload16(vs + 512, vd + 512);
  };

#define ITERBODY(KB, BUF)                                                     \
  {                                                                           \
    const u16* KL = KlB + (half*2 + (BUF))*4096 + lane*8;                     \
    const u16* VL = VlB + (half*2 + (BUF))*4096 + lane*8;                     \
    const float rhv = bf2f(rhbase[KB]);                                       \
    f32x4 s[4];                                                               \
    _Pragma("unroll")                                                         \
    for (int ct = 0; ct < 4; ++ct){                                           \
      _Pragma("unroll")                                                       \
      for (int r = 0; r < 4; ++r) s[ct][r] = rhv + rwf[ct][r];                \
    }                                                                         \
    __builtin_amdgcn_s_setprio(1);                                            \
    _Pragma("unroll")                                                         \
    for (int ct = 0; ct < 4; ++ct){                                           \
      s[ct] = MFMA(ld8(KL + (ct*2)*512),   qf0, s[ct], 0, 0, 0);              \
      s[ct] = MFMA(ld8(KL + (ct*2+1)*512), qf1, s[ct], 0, 0, 0);              \
    }                                                                         \
    __builtin_amdgcn_s_setprio(0);                                            \
    /* lane-local max over own 16 values */                                   \
    float pm0 = fmaxf(fmaxf(s[0][0], s[0][1]), fmaxf(fmaxf(s[0][2], s[0][3]), \
                      fmaxf(s[1][0], s[1][1])));                              \
    float pm1 = fmaxf(fmaxf(s[1][2], s[1][3]), fmaxf(fmaxf(s[2][0], s[2][1]), \
                      fmaxf(s[2][2], s[2][3])));                              \
    float pm2 = fmaxf(fmaxf(s[3][0], s[3][1]), fmaxf(s[3][2], s[3][3]));      \
    float pm = fmaxf(fmaxf(pm0, pm1), pm2);                                   \
    /* lazy rescale: cross-lane reduce only when some row max grew */         \
    if (__any(pm > m)){                                                       \
      pm = fmaxf(pm, __shfl_xor(pm, 16, 64));                                 \
      pm = fmaxf(pm, __shfl_xor(pm, 32, 64));                                 \
      const float nm = fmaxf(m, pm);                                          \
      const float corr = EXP2(m - nm);                                        \
      m = nm;                                                                 \
      lsum *= corr;                                                           \
      _Pragma("unroll")                                                       \
      for (int dt = 0; dt < 4; ++dt)                                          \
        _Pragma("unroll")                                                     \
        for (int r = 0; r < 4; ++r) oacc[dt][r] *= corr;                      \
    }                                                                         \
    float rs = 0.f;                                                           \
    _Pragma("unroll")                                                         \
    for (int ct = 0; ct < 4; ++ct){                                           \
      _Pragma("unroll")                                                       \
      for (int r = 0; r < 4; ++r){                                            \
        float p2 = EXP2(s[ct][r] - m);                                        \
        s[ct][r] = p2; rs += p2;                                              \
      }                                                                       \
    }                                                                         \
    lsum += rs;                                                               \
    _Pragma("unroll")                                                         \
    for (int ct = 0; ct < 4; ++ct){                                           \
      uint2 uv;                                                               \
      uv.x = cvtpk(s[ct][0], s[ct][1]);                                       \
      uv.y = cvtpk(s[ct][2], s[ct][3]);                                       \
      *(uint2*)(Pb + ((lr*128 + ct*32 + lg*8) ^ swz)) = uv;                   \
    }                                                                         \
    bf16x8 pa0 = __builtin_bit_cast(bf16x8, *(ushort8*)(Pb + ((lr*128      + lg*16) ^ swz))); \
    bf16x8 pa1 = __builtin_bit_cast(bf16x8, *(ushort8*)(Pb + ((lr*128 + 64 + lg*16) ^ swz))); \
    __builtin_amdgcn_s_setprio(1);                                            \
    _Pragma("unroll")                                                         \
    for (int dt = 0; dt < 4; ++dt){                                           \
      oacc[dt] = MFMA(ld8(VL + (dt*2)*512),   pa0, oacc[dt], 0, 0, 0);        \
      oacc[dt] = MFMA(ld8(VL + (dt*2+1)*512), pa1, oacc[dt], 0, 0, 0);        \
    }                                                                         \
    __builtin_amdgcn_s_setprio(0);                                            \
  }

  stage(0, 0);
  __syncthreads();                     // drains vmcnt -> tile 0 ready
  for (int kl = 0; kl < 32; kl += 2){
    stage(1, kl + 1);                  // issue next-tile loads (overlap compute)
    ITERBODY(kb0 + kl, 0)
    __syncthreads();                   // buf1 staged + all waves done with buf0
    if (kl < 30) stage(0, kl + 2);     // skip useless final prefetch (Osm aliases Kl!)
    ITERBODY(kb0 + kl + 1, 1)
    __syncthreads();
  }
#undef ITERBODY

  // ---- pairwise merge across KV halves (reuses staging LDS; all DMA drained) ----
  lsum += __shfl_xor(lsum, 16, 64);
  lsum += __shfl_xor(lsum, 32, 64);
  {
    float* Ow = (float*)SMEM + w*1088;           // [16 q][68] padded
    #pragma unroll
    for (int dt = 0; dt < 4; ++dt)
      *(f32x4*)&Ow[lr*68 + dt*16 + lg*4] = oacc[dt];
    if (lg == 0){
      float* ML = (float*)(SMEM + 34816) + w*32;
      ML[lr] = m;
      ML[16 + lr] = lsum;
    }
  }
  __syncthreads();
  {
    const int qt2 = tid >> 7, q16 = (tid >> 3) & 15, dq = tid & 7;
    const int w0 = qt2, w1 = qt2 + 4;
    const float* ML0 = (const float*)(SMEM + 34816) + w0*32;
    const float* ML1 = (const float*)(SMEM + 34816) + w1*32;
    const float m0 = ML0[q16], m1 = ML1[q16];
    const float l0 = ML0[16 + q16], l1 = ML1[16 + q16];
    const float ms = fmaxf(m0, m1);
    const float s0 = EXP2(m0 - ms), s1 = EXP2(m1 - ms);
    const float inv = 1.0f / (s0*l0 + s1*l1);
    const float* O0 = (const float*)SMEM + w0*1088 + q16*68 + dq*8;
    const float* O1 = (const float*)SMEM + w1*1088 + q16*68 + dq*8;
    f32x4 a0 = *(const f32x4*)O0, a1 = *(const f32x4*)(O0 + 4);
    f32x4 b0 = *(const f32x4*)O1, b1 = *(const f32x4*)(O1 + 4);
    float v[8];
    #pragma unroll
    for (int j = 0; j < 4; ++j){
      v[j]     = (s0*a0[j] + s1*b0[j])*inv;
      v[j + 4] = (s0*a1[j] + s1*b1[j])*inv;
    }
    uint4 outv;
    outv.x = cvtpk(v[0], v[1]); outv.y = cvtpk(v[2], v[3]);
    outv.z = cvtpk(v[4], v[5]); outv.w = cvtpk(v[6], v[7]);
    const int qg = qb*64 + qt2*16 + q16;
    *(uint4*)&Ob[(size_t)qg*768 + h*64 + dq*8] = outv;
  }
}

// ---------------- proj GEMM: (4096x768)x(768x768) + b -> f32 out ----------------

__global__ __launch_bounds__(256) void k_proj(const u16* __restrict__ A, const u16* __restrict__ WT,
                                              const float* __restrict__ bias, float* __restrict__ out){
  __shared__ __align__(16) u16 At[128*64];
  __shared__ __align__(16) u16 Bt[128*64];
  const int tid = threadIdx.x, lane = tid & 63, w = tid >> 6;
  const int m0 = blockIdx.x*128, n0 = blockIdx.y*128;
  const int wr = (w >> 1)*64, wc = (w & 1)*64;
  const int lr = lane & 15, lg = lane >> 4;
  const int srcRow = w*32 + (lane >> 3);
  const int srcK   = (lane & 7)*8;
  f32x4 acc[4][4] = {};
  for (int kt = 0; kt < 12; ++kt){
    const int kbase = kt*64;
    for (int s = 0; s < 4; ++s){
      gload16(A  + (size_t)(m0 + srcRow + s*8)*768 + kbase + srcK, At + (w*32 + s*8)*64);
      gload16(WT + (size_t)(n0 + srcRow + s*8)*768 + kbase + srcK, Bt + (w*32 + s*8)*64);
    }
    __syncthreads();
    bf16x8 af[2][4], bfr[2][4];
    for (int ks = 0; ks < 2; ++ks)
      for (int i = 0; i < 4; ++i){
        af[ks][i]  = ld8(At + (wr + i*16 + lr)*64 + ks*32 + lg*8);
        bfr[ks][i] = ld8(Bt + (wc + i*16 + lr)*64 + ks*32 + lg*8);
      }
    for (int ks = 0; ks < 2; ++ks)
      for (int mi = 0; mi < 4; ++mi)
        for (int ni = 0; ni < 4; ++ni)
          acc[mi][ni] = MFMA(af[ks][mi], bfr[ks][ni], acc[mi][ni], 0, 0, 0);
    __syncthreads();
  }
  for (int mi = 0; mi < 4; ++mi)
    for (int ni = 0; ni < 4; ++ni){
      int col = n0 + wc + ni*16 + lr;
      float bv = bias[col];
      for (int r = 0; r < 4; ++r){
        int row = m0 + wr + mi*16 + lg*4 + r;
        out[(size_t)row*768 + col] = acc[mi][ni][r] + bv;
      }
    }
}

// ---------------- launch ----------------

extern "C" void kernel_launch(void* const* d_in, const int* in_sizes, int n_in,
                              void* d_out, int out_size, void* d_ws, size_t ws_size,
                              hipStream_t stream){
  const float* X32   = (const float*)d_in[0];
  const float* qkvw  = (const float*)d_in[1];
  const float* qkvb  = (const float*)d_in[2];
  const float* projw = (const float*)d_in[3];
  const float* projb = (const float*)d_in[4];
  const float* rposh = (const float*)d_in[5];
  const float* rposw = (const float*)d_in[6];

  u16* Xb  = (u16*)d_ws;            // 4096*768
  u16* W1T = Xb  + 3145728;         // 2304*768
  u16* PT  = W1T + 1769472;         // 768*768
  u16* Rh8 = PT  + 589824;          // 128*64 (padded)
  u16* Rw8 = Rh8 + 8192;            // 128*64 (padded)
  u16* Qs  = Rw8 + 8192;            // 12*4096*64 (pre-scaled by 1/8 * log2e)
  u16* Kf  = Qs  + 3145728;         // fragment-linear K [12][64][8][64][8]
  u16* Vf  = Kf  + 3145728;         // fragment-linear V^T [12][64][8][64][8]
  u16* Rlh = Vf  + 3145728;         // [12][4096][64]
  u16* Rlw = Rlh + 3145728;         // [12][4096][64]
  u16* Ob  = Rlw + 3145728;         // [4096][768]
  float* out = (float*)d_out;

  k_prep <<<2176, 256, 0, stream>>>(X32, qkvw, projw, rposh, rposw, Xb, W1T, PT, Rh8, Rw8);
  k_qkv  <<<dim3(32, 18), 256, 0, stream>>>(Xb, W1T, qkvb, Qs, Kf, Vf);
  k_rel  <<<dim3(64, 12), 256, 0, stream>>>(Qs, Rh8, Rw8, Rlh, Rlw);
  k_flash<<<768, 512, 0, stream>>>(Qs, Kf, Vf, Rlh, Rlw, Ob);
  k_proj <<<dim3(32, 6), 256, 0, stream>>>(Ob, PT, projb, out);
}

// Round 14
// 161.951 us; speedup vs baseline: 1.1090x; 1.0886x over previous
//
#include <hip/hip_runtime.h>
#include <stdint.h>

typedef unsigned short u16;
typedef __bf16 bf16x8 __attribute__((ext_vector_type(8)));
typedef float f32x4 __attribute__((ext_vector_type(4)));
typedef unsigned short ushort8 __attribute__((ext_vector_type(8)));
typedef unsigned short ushort4v __attribute__((ext_vector_type(4)));
typedef uint32_t uint4v __attribute__((ext_vector_type(4)));

#define MFMA __builtin_amdgcn_mfma_f32_16x16x32_bf16
#define EXP2 __builtin_amdgcn_exp2f

__device__ __forceinline__ u16 f2bf(float f){
  uint32_t u = __builtin_bit_cast(uint32_t, f);
  u += 0x7fffu + ((u >> 16) & 1u);
  return (u16)(u >> 16);
}
__device__ __forceinline__ float bf2f(u16 h){
  uint32_t u = ((uint32_t)h) << 16;
  return __builtin_bit_cast(float, u);
}
__device__ __forceinline__ uint32_t cvtpk(float lo, float hi){
  uint32_t r;
  asm("v_cvt_pk_bf16_f32 %0, %1, %2" : "=v"(r) : "v"(lo), "v"(hi));
  return r;
}
__device__ __forceinline__ bf16x8 ld8(const u16* p){
  return __builtin_bit_cast(bf16x8, *(const ushort8*)p);
}
__device__ __forceinline__ void gload16(const void* g, void* l){
  __builtin_amdgcn_global_load_lds((__attribute__((address_space(1))) void*)(void*)g,
                                   (__attribute__((address_space(3))) void*)l, 16, 0, 0);
}

// ---------------- fused preprocessing: conv8 | tr(qkv_w) | tr(proj_w) | relconv ----------------

__device__ __forceinline__ void tr_body(const float* __restrict__ in, u16* __restrict__ out,
                                        int R, int Cc, int bx, int by, int t, float* tile /*64x65*/){
  int r0 = bx*64, c0 = by*64;
  int c = t & 63, r4 = t >> 6;
  for (int i = 0; i < 16; ++i)
    tile[(r4 + i*4)*65 + c] = in[(size_t)(r0 + r4 + i*4)*Cc + c0 + c];
  __syncthreads();
  for (int i = 0; i < 16; ++i){
    int rr = r4 + i*4;
    out[(size_t)(c0 + rr)*R + r0 + c] = f2bf(tile[c*65 + rr]);
  }
}

__global__ __launch_bounds__(256) void k_prep(const float* __restrict__ X32,
                                              const float* __restrict__ qkvw,
                                              const float* __restrict__ projw,
                                              const float* __restrict__ rposh,
                                              const float* __restrict__ rposw,
                                              u16* __restrict__ Xb, u16* __restrict__ W1T,
                                              u16* __restrict__ PT,
                                              u16* __restrict__ rh8, u16* __restrict__ rw8){
  __shared__ float tile[64*65];
  const int b = blockIdx.x, t = threadIdx.x;
  if (b < 1536){
    int i = b*256 + t;
    const float4* p = (const float4*)X32;
    float4 a = p[i*2], c = p[i*2+1];
    ushort8 o;
    o[0]=f2bf(a.x); o[1]=f2bf(a.y); o[2]=f2bf(a.z); o[3]=f2bf(a.w);
    o[4]=f2bf(c.x); o[5]=f2bf(c.y); o[6]=f2bf(c.z); o[7]=f2bf(c.w);
    ((ushort8*)Xb)[i] = o;
  } else if (b < 1968){
    int bb = b - 1536;
    tr_body(qkvw, W1T, 768, 2304, bb % 12, bb / 12, t, tile);
  } else if (b < 2112){
    int bb = b - 1968;
    tr_body(projw, PT, 768, 768, bb % 12, bb / 12, t, tile);
  } else {
    int i = (b - 2112)*256 + t;          // [0,16384)
    if (i < 8192)      rh8[i] = f2bf(i < 8128 ? rposh[i]*8.0f : 0.0f);
    else { int j = i - 8192; rw8[j] = f2bf(j < 8128 ? rposw[j]*8.0f : 0.0f); }
  }
}

// ---------------- QKV GEMM: (4096x768)x(768x2304), split to Qs/Kf/Vf ----------------
// K fragment-linear:  Kf[h][kb][f=ct*2+ks][lane=lg*16+lr][e] = K[kb*64+ct*16+lr][ks*32+lg*8+e]
// V fragment-linear with PERMUTED k (pi(lg,e) = (e>>2)*16 + lg*4 + (e&3)) so the
// flash PV B-operand can be assembled IN-REGISTER from the swapped-QK^T output
// (no P LDS roundtrip):
//   Vf[h][kb][f=dt*2+ks][lane=lg*16+lr][e] = V[kb*64 + ks*32 + pi(lg,e)][dt*16+lr]

__global__ __launch_bounds__(256) void k_qkv(const u16* __restrict__ X, const u16* __restrict__ WT,
                                             const float* __restrict__ bias,
                                             u16* __restrict__ Qs, u16* __restrict__ Kf, u16* __restrict__ Vf){
  __shared__ __align__(16) u16 At[128*64];
  __shared__ __align__(16) u16 Bt[128*64];
  __shared__ __align__(16) u16 Tt[4][64*72];   // per-wave repack tile, pad 72 keeps 16B align
  const int tid = threadIdx.x, lane = tid & 63, w = tid >> 6;
  const int m0 = blockIdx.x*128, n0 = blockIdx.y*128;
  const int wr = (w >> 1)*64, wc = (w & 1)*64;
  const int lr = lane & 15, lg = lane >> 4;
  const int srcRow = w*32 + (lane >> 3);
  const int srcK   = (lane & 7)*8;
  f32x4 acc[4][4] = {};
  for (int kt = 0; kt < 12; ++kt){
    const int kbase = kt*64;
    for (int s = 0; s < 4; ++s){
      gload16(X  + (size_t)(m0 + srcRow + s*8)*768 + kbase + srcK, At + (w*32 + s*8)*64);
      gload16(WT + (size_t)(n0 + srcRow + s*8)*768 + kbase + srcK, Bt + (w*32 + s*8)*64);
    }
    __syncthreads();
    bf16x8 af[2][4], bfr[2][4];
    for (int ks = 0; ks < 2; ++ks)
      for (int i = 0; i < 4; ++i){
        af[ks][i]  = ld8(At + (wr + i*16 + lr)*64 + ks*32 + lg*8);
        bfr[ks][i] = ld8(Bt + (wc + i*16 + lr)*64 + ks*32 + lg*8);
      }
    for (int ks = 0; ks < 2; ++ks)
      for (int mi = 0; mi < 4; ++mi)
        for (int ni = 0; ni < 4; ++ni)
          acc[mi][ni] = MFMA(af[ks][mi], bfr[ks][ni], acc[mi][ni], 0, 0, 0);
    __syncthreads();
  }
  const int colbase = n0 + wc;            // 64-aligned -> s3/hh uniform per wave
  const int s3 = colbase / 768;
  const int hh = (colbase % 768) >> 6;
  const int rowbase = m0 + wr;            // 64-aligned -> kb uniform per wave
  if (s3 == 0){
    for (int mi = 0; mi < 4; ++mi)
      for (int ni = 0; ni < 4; ++ni){
        float bv = bias[colbase + ni*16 + lr];
        for (int r = 0; r < 4; ++r){
          int row = rowbase + mi*16 + lg*4 + r;
          // Q pre-scaled by head_dim^-0.5 * log2(e) so softmax runs in exp2 domain
          Qs[((size_t)hh*4096 + row)*64 + ni*16 + lr] =
              f2bf((acc[mi][ni][r] + bv)*(0.125f*1.44269504f));
        }
      }
  } else {
    u16* T = Tt[w];
    for (int mi = 0; mi < 4; ++mi)
      for (int ni = 0; ni < 4; ++ni){
        float bv = bias[colbase + ni*16 + lr];
        for (int r = 0; r < 4; ++r){
          int row_l = mi*16 + lg*4 + r, col_l = ni*16 + lr;
          u16 v = f2bf(acc[mi][ni][r] + bv);
          if (s3 == 1) T[row_l*72 + col_l] = v;     // K: [token][d]
          else         T[col_l*72 + row_l] = v;     // V: [d][token] (transposed)
        }
      }
    // same-wave LDS write->read; no cross-wave sharing, compiler inserts lgkmcnt
    const int kb = rowbase >> 6;
    u16* dst = (s3 == 1 ? Kf : Vf) + ((size_t)hh*64 + kb)*4096 + lane*8;
    if (s3 == 1){
      #pragma unroll
      for (int f = 0; f < 8; ++f){
        int a = f >> 1, ks = f & 1;
        *(ushort8*)&dst[f*512] = *(const ushort8*)&T[(a*16 + lr)*72 + ks*32 + lg*8];
      }
    } else {
      // permuted-k V fragments: elems 0-3 <- tokens ks*32+lg*4+(0..3),
      //                         elems 4-7 <- tokens ks*32+16+lg*4+(0..3)
      #pragma unroll
      for (int f = 0; f < 8; ++f){
        int a = f >> 1, ks = f & 1;
        const int rowb = (a*16 + lr)*72 + ks*32 + lg*4;
        ushort4v lo = *(const ushort4v*)&T[rowb];
        ushort4v hi = *(const ushort4v*)&T[rowb + 16];
        ushort8 o;
        o[0]=lo[0]; o[1]=lo[1]; o[2]=lo[2]; o[3]=lo[3];
        o[4]=hi[0]; o[5]=hi[1]; o[6]=hi[2]; o[7]=hi[3];
        *(ushort8*)&dst[f*512] = o;
      }
    }
  }
}

// ---------------- rel_h / rel_w via MFMA; grid (64 qh, 12 h) ----------------

__global__ __launch_bounds__(256) void k_rel(const u16* __restrict__ Qs, const u16* __restrict__ Rh8,
                                             const u16* __restrict__ Rw8,
                                             u16* __restrict__ relh, u16* __restrict__ relw){
  __shared__ __align__(16) u16 Ql[64*64];
  __shared__ __align__(16) u16 Rhl[64*64];
  __shared__ __align__(16) u16 Rwl[128*64];
  const int tid = threadIdx.x, lane = tid & 63, w = tid >> 6;
  const int qh = blockIdx.x, h = blockIdx.y;
  const int lr = lane & 15, lg = lane >> 4;
  for (int j = 0; j < 2; ++j){
    int ch = tid + 256*j;             // 0..511
    int row = ch >> 3, k8 = (ch & 7)*8;
    *(ushort8*)&Ql[row*64 + k8]  = *(const ushort8*)&Qs[((size_t)h*4096 + qh*64 + row)*64 + k8];
    *(ushort8*)&Rhl[row*64 + k8] = *(const ushort8*)&Rh8[(qh + row)*64 + k8];
  }
  for (int j = 0; j < 4; ++j){
    int ch = tid + 256*j;             // 0..1023
    int row = ch >> 3, k8 = (ch & 7)*8;
    *(ushort8*)&Rwl[row*64 + k8] = *(const ushort8*)&Rw8[row*64 + k8];
  }
  __syncthreads();
  bf16x8 a[2];
  for (int ks = 0; ks < 2; ++ks) a[ks] = ld8(Ql + (w*16 + lr)*64 + ks*32 + lg*8);
  // rel_h[qw][kh] = (Q . rel_pos_h[qh+63-kh]) ; computed as Q @ Rh[qh+c]^T, kh = 63-c
  for (int ct = 0; ct < 4; ++ct){
    f32x4 c = {};
    for (int ks = 0; ks < 2; ++ks)
      c = MFMA(a[ks], ld8(Rhl + (ct*16 + lr)*64 + ks*32 + lg*8), c, 0, 0, 0);
    int kh = 63 - (ct*16 + lr);
    for (int r = 0; r < 4; ++r){
      int qw = w*16 + lg*4 + r;
      relh[((size_t)h*4096 + qh*64 + qw)*64 + kh] = f2bf(c[r]);
    }
  }
  // rel_w[qw][kw] = (Q . rel_pos_w[qw+63-kw]) ; full band, keep valid kw
  for (int ct = 0; ct < 8; ++ct){
    f32x4 c = {};
    for (int ks = 0; ks < 2; ++ks)
      c = MFMA(a[ks], ld8(Rwl + (ct*16 + lr)*64 + ks*32 + lg*8), c, 0, 0, 0);
    int cc = ct*16 + lr;
    for (int r = 0; r < 4; ++r){
      int qw = w*16 + lg*4 + r;
      int kw = qw + 63 - cc;
      if (kw >= 0 && kw < 64)
        relw[((size_t)h*4096 + qh*64 + qw)*64 + kw] = f2bf(c[r]);
    }
  }
}

// ---------------- flash attention; flat grid 768, 4 waves ----------------
// R14 = R11 structure (K+V LDS-staged per block, double-buffered, shared by
// 4 waves; lazy softmax; swapped operands) MINUS the P LDS roundtrip:
// PV B-operand (P^T fragments) assembled IN-REGISTER from the QK^T output via
// 8 cvt_pk — valid because Vf is stored with the matching k-permutation
// pi(lg,e) (MFMA contracts Sum_pos A[d][pos]*B[pos][q]; permuting pos
// consistently in A and B is exact). Removes 4 ds_write + 2 ds_read + lgkm
// wait (~150-250cy/iter critical path) and ALL P bank conflicts (3.2M).
// Head->XCD affinity (768 = 8*96): <=2 heads (2MB KV) per XCD L2.
// launch_bounds(256,3): arch-VGPR budget ~84; spill tripwire = FETCH_SIZE.

__global__ __launch_bounds__(256, 3) void k_flash(const u16* __restrict__ Qs, const u16* __restrict__ Kf,
                                                  const u16* __restrict__ Vf,
                                                  const u16* __restrict__ relh, const u16* __restrict__ relw,
                                                  u16* __restrict__ Ob){
  __shared__ __align__(16) u16 Kl[2][4096];       // 8KB per K tile (fragment-linear copy)
  __shared__ __align__(16) u16 Vl[2][4096];       // 8KB per V tile (permuted-k layout)
  const int tid = threadIdx.x, lane = tid & 63, w = tid >> 6;
  const int b = blockIdx.x;
  const int p = (b & 7)*96 + (b >> 3);         // head->XCD affinity remap (768 = 8*96)
  const int h = p >> 6, qb = p & 63;
  const int lr = lane & 15, lg = lane >> 4;
  const size_t hq = (size_t)h*4096;
  const int q = qb*64 + w*16 + lr;             // this lane's q row (S^T column)

  const bf16x8 qf0 = ld8(Qs + (hq + q)*64 + lg*8);
  const bf16x8 qf1 = ld8(Qs + (hq + q)*64 + 32 + lg*8);
  // rel_w bias row unpacked to f32 once
  float rwf[4][4];
  #pragma unroll
  for (int ct = 0; ct < 4; ++ct){
    ushort4v t = *(const ushort4v*)&relw[(hq + q)*64 + ct*16 + lg*4];
    #pragma unroll
    for (int r = 0; r < 4; ++r) rwf[ct][r] = bf2f(t[r]);
  }

  const u16* KfH = Kf + (size_t)h*262144;      // + kb*4096
  const u16* VfH = Vf + (size_t)h*262144;
  const u16* rhbase = relh + (hq + q)*64;

  float m = -1e30f, lsum = 0.f;                // lsum per-lane partial (reduced at end)
  f32x4 oacc[4] = {};                          // O^T: rows d = dt*16+lg*4+r, col q = lr

  // wave w stages 1KB chunks {2w, 2w+1} of K and V (8 chunks each, 4 waves).
  // global src per-lane (+lane*8 elems); LDS dest wave-uniform (HW adds lane*16B).
  auto stage = [&](int buf, int kb){
    const u16* ks = KfH + kb*4096 + w*1024 + lane*8;
    const u16* vs = VfH + kb*4096 + w*1024 + lane*8;
    gload16(ks,       &Kl[buf][w*1024]);
    gload16(ks + 512, &Kl[buf][w*1024 + 512]);
    gload16(vs,       &Vl[buf][w*1024]);
    gload16(vs + 512, &Vl[buf][w*1024 + 512]);
  };

#define ITERBODY(KB, BUF)                                                     \
  {                                                                           \
    const u16* KL = Kl[BUF] + lane*8;                                         \
    const u16* VL = Vl[BUF] + lane*8;                                         \
    const float rhv = bf2f(rhbase[KB]);                                       \
    f32x4 s[4];                                                               \
    _Pragma("unroll")                                                         \
    for (int ct = 0; ct < 4; ++ct){                                           \
      _Pragma("unroll")                                                       \
      for (int r = 0; r < 4; ++r) s[ct][r] = rhv + rwf[ct][r];                \
    }                                                                         \
    __builtin_amdgcn_s_setprio(1);                                            \
    _Pragma("unroll")                                                         \
    for (int ct = 0; ct < 4; ++ct){                                           \
      s[ct] = MFMA(ld8(KL + (ct*2)*512),   qf0, s[ct], 0, 0, 0);              \
      s[ct] = MFMA(ld8(KL + (ct*2+1)*512), qf1, s[ct], 0, 0, 0);              \
    }                                                                         \
    __builtin_amdgcn_s_setprio(0);                                            \
    /* lane-local max over own 16 values */                                   \
    float pm0 = fmaxf(fmaxf(s[0][0], s[0][1]), fmaxf(fmaxf(s[0][2], s[0][3]), \
                      fmaxf(s[1][0], s[1][1])));                              \
    float pm1 = fmaxf(fmaxf(s[1][2], s[1][3]), fmaxf(fmaxf(s[2][0], s[2][1]), \
                      fmaxf(s[2][2], s[2][3])));                              \
    float pm2 = fmaxf(fmaxf(s[3][0], s[3][1]), fmaxf(s[3][2], s[3][3]));      \
    float pm = fmaxf(fmaxf(pm0, pm1), pm2);                                   \
    /* lazy rescale: cross-lane reduce only when some row max grew */         \
    if (__any(pm > m)){                                                       \
      pm = fmaxf(pm, __shfl_xor(pm, 16, 64));                                 \
      pm = fmaxf(pm, __shfl_xor(pm, 32, 64));                                 \
      const float nm = fmaxf(m, pm);                                          \
      const float corr = EXP2(m - nm);                                        \
      m = nm;                                                                 \
      lsum *= corr;                                                           \
      _Pragma("unroll")                                                       \
      for (int dt = 0; dt < 4; ++dt)                                          \
        _Pragma("unroll")                                                     \
        for (int r = 0; r < 4; ++r) oacc[dt][r] *= corr;                      \
    }                                                                         \
    float rs = 0.f;                                                           \
    _Pragma("unroll")                                                         \
    for (int ct = 0; ct < 4; ++ct){                                           \
      _Pragma("unroll")                                                       \
      for (int r = 0; r < 4; ++r){                                            \
        float p2 = EXP2(s[ct][r] - m);                                        \
        s[ct][r] = p2; rs += p2;                                              \
      }                                                                       \
    }                                                                         \
    lsum += rs;   /* per-lane partial; no shfl here */                        \
    /* P^T B-fragments in-register (k-permuted to match Vf layout) */         \
    uint4v u0, u1;                                                            \
    u0[0] = cvtpk(s[0][0], s[0][1]); u0[1] = cvtpk(s[0][2], s[0][3]);         \
    u0[2] = cvtpk(s[1][0], s[1][1]); u0[3] = cvtpk(s[1][2], s[1][3]);         \
    u1[0] = cvtpk(s[2][0], s[2][1]); u1[1] = cvtpk(s[2][2], s[2][3]);         \
    u1[2] = cvtpk(s[3][0], s[3][1]); u1[3] = cvtpk(s[3][2], s[3][3]);         \
    bf16x8 pa0 = __builtin_bit_cast(bf16x8, u0);                              \
    bf16x8 pa1 = __builtin_bit_cast(bf16x8, u1);                              \
    __builtin_amdgcn_s_setprio(1);                                            \
    _Pragma("unroll")                                                         \
    for (int dt = 0; dt < 4; ++dt){                                           \
      oacc[dt] = MFMA(ld8(VL + (dt*2)*512),   pa0, oacc[dt], 0, 0, 0);        \
      oacc[dt] = MFMA(ld8(VL + (dt*2+1)*512), pa1, oacc[dt], 0, 0, 0);        \
    }                                                                         \
    __builtin_amdgcn_s_setprio(0);                                            \
  }

  stage(0, 0);
  __syncthreads();                     // drains vmcnt -> tile 0 ready
  for (int kb2 = 0; kb2 < 64; kb2 += 2){
    stage(1, (kb2 + 1) & 63);          // issue next-tile loads (overlap compute)
    ITERBODY(kb2, 0)
    __syncthreads();                   // buf1 staged + all waves done with buf0
    stage(0, (kb2 + 2) & 63);
    ITERBODY(kb2 + 1, 1)
    __syncthreads();
  }
#undef ITERBODY

  // epilogue: single cross-lane sum reduce of the per-lane lsum partials
  lsum += __shfl_xor(lsum, 16, 64);
  lsum += __shfl_xor(lsum, 32, 64);
  const float inv = 1.0f / lsum;
  #pragma unroll
  for (int dt = 0; dt < 4; ++dt){
    ushort4v pk;
    #pragma unroll
    for (int r = 0; r < 4; ++r) pk[r] = f2bf(oacc[dt][r]*inv);
    *(ushort4v*)&Ob[(size_t)q*768 + h*64 + dt*16 + lg*4] = pk;
  }
}

// ---------------- proj GEMM: (4096x768)x(768x768) + b -> f32 out ----------------

__global__ __launch_bounds__(256) void k_proj(const u16* __restrict__ A, const u16* __restrict__ WT,
                                              const float* __restrict__ bias, float* __restrict__ out){
  __shared__ __align__(16) u16 At[128*64];
  __shared__ __align__(16) u16 Bt[128*64];
  const int tid = threadIdx.x, lane = tid & 63, w = tid >> 6;
  const int m0 = blockIdx.x*128, n0 = blockIdx.y*128;
  const int wr = (w >> 1)*64, wc = (w & 1)*64;
  const int lr = lane & 15, lg = lane >> 4;
  const int srcRow = w*32 + (lane >> 3);
  const int srcK   = (lane & 7)*8;
  f32x4 acc[4][4] = {};
  for (int kt = 0; kt < 12; ++kt){
    const int kbase = kt*64;
    for (int s = 0; s < 4; ++s){
      gload16(A  + (size_t)(m0 + srcRow + s*8)*768 + kbase + srcK, At + (w*32 + s*8)*64);
      gload16(WT + (size_t)(n0 + srcRow + s*8)*768 + kbase + srcK, Bt + (w*32 + s*8)*64);
    }
    __syncthreads();
    bf16x8 af[2][4], bfr[2][4];
    for (int ks = 0; ks < 2; ++ks)
      for (int i = 0; i < 4; ++i){
        af[ks][i]  = ld8(At + (wr + i*16 + lr)*64 + ks*32 + lg*8);
        bfr[ks][i] = ld8(Bt + (wc + i*16 + lr)*64 + ks*32 + lg*8);
      }
    for (int ks = 0; ks < 2; ++ks)
      for (int mi = 0; mi < 4; ++mi)
        for (int ni = 0; ni < 4; ++ni)
          acc[mi][ni] = MFMA(af[ks][mi], bfr[ks][ni], acc[mi][ni], 0, 0, 0);
    __syncthreads();
  }
  for (int mi = 0; mi < 4; ++mi)
    for (int ni = 0; ni < 4; ++ni){
      int col = n0 + wc + ni*16 + lr;
      float bv = bias[col];
      for (int r = 0; r < 4; ++r){
        int row = m0 + wr + mi*16 + lg*4 + r;
        out[(size_t)row*768 + col] = acc[mi][ni][r] + bv;
      }
    }
}

// ---------------- launch ----------------

extern "C" void kernel_launch(void* const* d_in, const int* in_sizes, int n_in,
                              void* d_out, int out_size, void* d_ws, size_t ws_size,
                              hipStream_t stream){
  const float* X32   = (const float*)d_in[0];
  const float* qkvw  = (const float*)d_in[1];
  const float* qkvb  = (const float*)d_in[2];
  const float* projw = (const float*)d_in[3];
  const float* projb = (const float*)d_in[4];
  const float* rposh = (const float*)d_in[5];
  const float* rposw = (const float*)d_in[6];

  u16* Xb  = (u16*)d_ws;            // 4096*768
  u16* W1T = Xb  + 3145728;         // 2304*768
  u16* PT  = W1T + 1769472;         // 768*768
  u16* Rh8 = PT  + 589824;          // 128*64 (padded)
  u16* Rw8 = Rh8 + 8192;            // 128*64 (padded)
  u16* Qs  = Rw8 + 8192;            // 12*4096*64 (pre-scaled by 1/8 * log2e)
  u16* Kf  = Qs  + 3145728;         // fragment-linear K [12][64][8][64][8]
  u16* Vf  = Kf  + 3145728;         // fragment-linear V^T, k-permuted [12][64][8][64][8]
  u16* Rlh = Vf  + 3145728;         // [12][4096][64]
  u16* Rlw = Rlh + 3145728;         // [12][4096][64]
  u16* Ob  = Rlw + 3145728;         // [4096][768]
  float* out = (float*)d_out;

  k_prep <<<2176, 256, 0, stream>>>(X32, qkvw, projw, rposh, rposw, Xb, W1T, PT, Rh8, Rw8);
  k_qkv  <<<dim3(32, 18), 256, 0, stream>>>(Xb, W1T, qkvb, Qs, Kf, Vf);
  k_rel  <<<dim3(64, 12), 256, 0, stream>>>(Qs, Rh8, Rw8, Rlh, Rlw);
  k_flash<<<768, 256, 0, stream>>>(Qs, Kf, Vf, Rlh, Rlw, Ob);
  k_proj <<<dim3(32, 6), 256, 0, stream>>>(Ob, PT, projb, out);
}